// Round 1
// baseline (61.231 us; speedup 1.0000x reference)
//
#include <hip/hip_runtime.h>

// Problem constants (match reference)
constexpr int B = 128, N = 900, C = 91, M = 100;
constexpr float ALPHA = 0.25f;
constexpr float W_CLASS = 2.0f;
constexpr float W_BBOX = 5.0f;
constexpr float W_GIOU = 2.0f;
constexpr float EPS = 1e-8f;

constexpr int ROWS = 2;   // n-rows per block

__global__ __launch_bounds__(256) void hungarian_cost_kernel(
    const float* __restrict__ logits,   // [B, N, C]
    const float* __restrict__ pboxes,   // [B, N, 4] cxcywh
    const int*   __restrict__ tlabels,  // [B, M]
    const float* __restrict__ tboxes,   // [B, M, 4] cxcywh
    float* __restrict__ out)            // [B, N, M]
{
    // Target staging (per batch b)
    __shared__ float t_cx[M], t_cy[M], t_w[M], t_h[M];
    __shared__ float t_x0[M], t_y0[M], t_x1[M], t_y1[M], t_area[M];
    __shared__ int   t_lab[M];
    // Per-row class costs + pred box data
    __shared__ float cls[ROWS][C + 1];
    __shared__ float pb[ROWS][12];   // cx,cy,w,h,x0,y0,x1,y1,area

    const int b   = blockIdx.y;
    const int n0  = blockIdx.x * ROWS;
    const int tid = threadIdx.x;

    // ---- Phase A: stage targets ----
    if (tid < M) {
        const float4 tb = reinterpret_cast<const float4*>(tboxes)[b * M + tid];
        t_cx[tid] = tb.x; t_cy[tid] = tb.y; t_w[tid] = tb.z; t_h[tid] = tb.w;
        const float x0 = tb.x - 0.5f * tb.z;
        const float y0 = tb.y - 0.5f * tb.w;
        const float x1 = tb.x + 0.5f * tb.z;
        const float y1 = tb.y + 0.5f * tb.w;
        t_x0[tid] = x0; t_y0[tid] = y0; t_x1[tid] = x1; t_y1[tid] = y1;
        t_area[tid] = (x1 - x0) * (y1 - y0);
        t_lab[tid] = tlabels[b * M + tid];
    }

    // ---- Phase B: per-row focal class costs + pred box ----
    const int r    = tid >> 7;       // 0..ROWS-1
    const int lane = tid & 127;
    const int n    = n0 + r;

    if (lane < C) {
        const float x = logits[(b * N + n) * C + lane];
        const float s = 1.0f / (1.0f + __expf(-x));
        const float neg = (1.0f - ALPHA) * s * s * (-__logf(1.0f - s + EPS));
        const float pos = ALPHA * (1.0f - s) * (1.0f - s) * (-__logf(s + EPS));
        cls[r][lane] = pos - neg;
    }
    if (lane == C) {
        const float4 p = reinterpret_cast<const float4*>(pboxes)[b * N + n];
        pb[r][0] = p.x; pb[r][1] = p.y; pb[r][2] = p.z; pb[r][3] = p.w;
        const float x0 = p.x - 0.5f * p.z;
        const float y0 = p.y - 0.5f * p.w;
        const float x1 = p.x + 0.5f * p.z;
        const float y1 = p.y + 0.5f * p.w;
        pb[r][4] = x0; pb[r][5] = y0; pb[r][6] = x1; pb[r][7] = y1;
        pb[r][8] = (x1 - x0) * (y1 - y0);
    }
    __syncthreads();

    // ---- Phase C: compute 100 outputs per row ----
    if (lane < M) {
        const int m = lane;
        const float pcx = pb[r][0], pcy = pb[r][1], pw = pb[r][2], ph = pb[r][3];
        const float px0 = pb[r][4], py0 = pb[r][5], px1 = pb[r][6], py1 = pb[r][7];
        const float parea = pb[r][8];

        // L1 cdist on raw cxcywh
        const float l1 = fabsf(pcx - t_cx[m]) + fabsf(pcy - t_cy[m]) +
                         fabsf(pw  - t_w[m])  + fabsf(ph  - t_h[m]);

        // GIoU on xyxy
        const float ix0 = fmaxf(px0, t_x0[m]);
        const float iy0 = fmaxf(py0, t_y0[m]);
        const float ix1 = fminf(px1, t_x1[m]);
        const float iy1 = fminf(py1, t_y1[m]);
        const float iw = fmaxf(ix1 - ix0, 0.0f);
        const float ih = fmaxf(iy1 - iy0, 0.0f);
        const float inter = iw * ih;
        const float uni = parea + t_area[m] - inter;
        const float iou = inter / uni;

        const float ex0 = fminf(px0, t_x0[m]);
        const float ey0 = fminf(py0, t_y0[m]);
        const float ex1 = fmaxf(px1, t_x1[m]);
        const float ey1 = fmaxf(py1, t_y1[m]);
        const float ew = fmaxf(ex1 - ex0, 0.0f);
        const float eh = fmaxf(ey1 - ey0, 0.0f);
        const float earea = ew * eh;
        const float giou = iou - (earea - uni) / earea;

        const float ccls = cls[r][t_lab[m]];
        const float cost = W_CLASS * ccls + W_BBOX * l1 + W_GIOU * (-giou);

        out[(size_t)(b * N + n) * M + m] = cost;
    }
}

extern "C" void kernel_launch(void* const* d_in, const int* in_sizes, int n_in,
                              void* d_out, int out_size, void* d_ws, size_t ws_size,
                              hipStream_t stream) {
    const float* logits  = (const float*)d_in[0];
    const float* pboxes  = (const float*)d_in[1];
    const int*   tlabels = (const int*)d_in[2];
    const float* tboxes  = (const float*)d_in[3];
    float* out = (float*)d_out;

    dim3 grid(N / ROWS, B);
    dim3 block(256);
    hipLaunchKernelGGL(hungarian_cost_kernel, grid, block, 0, stream,
                       logits, pboxes, tlabels, tboxes, out);
}

// Round 2
// 47.863 us; speedup vs baseline: 1.2793x; 1.2793x over previous
//
#include <hip/hip_runtime.h>

// Problem constants (match reference)
constexpr int B = 128, N = 900, C = 91, M = 100;
constexpr float ALPHA = 0.25f;
constexpr float W_CLASS = 2.0f;
constexpr float W_BBOX = 5.0f;
constexpr float W_GIOU = 2.0f;
constexpr float EPS = 1e-8f;

constexpr int ROWS = 36;          // n-rows per block (900 = 36 * 25)
constexpr int NBX  = N / ROWS;    // 25 blocks in n per batch
constexpr int BLK  = 256;
constexpr int MQ   = M / 4;       // 25 output quads per row

__global__ __launch_bounds__(BLK) void hungarian_cost_kernel(
    const float* __restrict__ logits,   // [B, N, C]
    const float* __restrict__ pboxes,   // [B, N, 4] cxcywh
    const int*   __restrict__ tlabels,  // [B, M]
    const float* __restrict__ tboxes,   // [B, M, 4] cxcywh
    float* __restrict__ out)            // [B, N, M]
{
    __shared__ float  cls[ROWS][C + 1];   // class cost, pre-scaled by W_CLASS
    __shared__ float4 t_box[M];           // target cxcywh
    __shared__ float4 t_xyxy[M];          // target xyxy
    __shared__ int    t_lab[M];
    __shared__ float  pb[ROWS][10];       // pred: cx,cy,w,h,x0,y0,x1,y1,area

    const int b   = blockIdx.y;
    const int n0  = blockIdx.x * ROWS;
    const int tid = threadIdx.x;

    // ---- Stage targets (threads 0..99) and pred boxes (threads 128..163) ----
    if (tid < M) {
        const float4 tb = reinterpret_cast<const float4*>(tboxes)[b * M + tid];
        t_box[tid] = tb;
        float4 tx;
        tx.x = tb.x - 0.5f * tb.z;  tx.y = tb.y - 0.5f * tb.w;
        tx.z = tb.x + 0.5f * tb.z;  tx.w = tb.y + 0.5f * tb.w;
        t_xyxy[tid] = tx;
        t_lab[tid]  = tlabels[b * M + tid];
    } else if (tid >= 128 && tid < 128 + ROWS) {
        const int r = tid - 128;
        const float4 p = reinterpret_cast<const float4*>(pboxes)[b * N + n0 + r];
        const float x0 = p.x - 0.5f * p.z, y0 = p.y - 0.5f * p.w;
        const float x1 = p.x + 0.5f * p.z, y1 = p.y + 0.5f * p.w;
        pb[r][0] = p.x; pb[r][1] = p.y; pb[r][2] = p.z; pb[r][3] = p.w;
        pb[r][4] = x0;  pb[r][5] = y0;  pb[r][6] = x1;  pb[r][7] = y1;
        pb[r][8] = (x1 - x0) * (y1 - y0);
    }

    // ---- Focal class costs: flat strided loop, coalesced logits reads ----
    const float* lrow = logits + ((size_t)(b * N) + n0) * C;
    for (int idx = tid; idx < ROWS * C; idx += BLK) {
        const float x = lrow[idx];
        const int row = idx / C;            // compiler magic-mul
        const int c   = idx - row * C;
        const float e  = __expf(-x);
        const float s  = __fdividef(1.0f, 1.0f + e);
        const float om = e * s;             // 1 - s
        const float pos = ALPHA         * om * om * (-__logf(s  + EPS));
        const float neg = (1.0f - ALPHA) * s * s  * (-__logf(om + EPS));
        cls[row][c] = W_CLASS * (pos - neg);
    }
    __syncthreads();

    // ---- Outputs: 4 consecutive m per thread, float4 stores ----
    float4* outq = reinterpret_cast<float4*>(out) + (size_t)(b * N + n0) * MQ;
    for (int q = tid; q < ROWS * MQ; q += BLK) {
        const int row = q / MQ;
        const int mq  = q - row * MQ;
        const int m0  = mq * 4;

        const float pcx = pb[row][0], pcy = pb[row][1], pw = pb[row][2], ph = pb[row][3];
        const float px0 = pb[row][4], py0 = pb[row][5], px1 = pb[row][6], py1 = pb[row][7];
        const float parea = pb[row][8];

        const int4 lab = reinterpret_cast<int4*>(t_lab)[mq];
        const int labs[4] = {lab.x, lab.y, lab.z, lab.w};

        float4 res;
        float* rp = &res.x;
        #pragma unroll
        for (int j = 0; j < 4; ++j) {
            const int m = m0 + j;
            const float4 tb = t_box[m];
            const float4 tx = t_xyxy[m];

            const float l1 = fabsf(pcx - tb.x) + fabsf(pcy - tb.y) +
                             fabsf(pw  - tb.z) + fabsf(ph  - tb.w);

            const float tarea = (tx.z - tx.x) * (tx.w - tx.y);
            const float iw = fmaxf(fminf(px1, tx.z) - fmaxf(px0, tx.x), 0.0f);
            const float ih = fmaxf(fminf(py1, tx.w) - fmaxf(py0, tx.y), 0.0f);
            const float inter = iw * ih;
            const float uni = parea + tarea - inter;

            const float ew = fmaxf(px1, tx.z) - fminf(px0, tx.x);
            const float eh = fmaxf(py1, tx.w) - fminf(py0, tx.y);
            const float earea = ew * eh;

            const float giou = __fdividef(inter, uni) - __fdividef(earea - uni, earea);

            rp[j] = cls[row][labs[j]] + W_BBOX * l1 - W_GIOU * giou;
        }
        outq[q] = res;
    }
}

extern "C" void kernel_launch(void* const* d_in, const int* in_sizes, int n_in,
                              void* d_out, int out_size, void* d_ws, size_t ws_size,
                              hipStream_t stream) {
    const float* logits  = (const float*)d_in[0];
    const float* pboxes  = (const float*)d_in[1];
    const int*   tlabels = (const int*)d_in[2];
    const float* tboxes  = (const float*)d_in[3];
    float* out = (float*)d_out;

    dim3 grid(NBX, B);
    dim3 block(BLK);
    hipLaunchKernelGGL(hungarian_cost_kernel, grid, block, 0, stream,
                       logits, pboxes, tlabels, tboxes, out);
}

// Round 3
// 43.066 us; speedup vs baseline: 1.4218x; 1.1114x over previous
//
#include <hip/hip_runtime.h>

// Problem constants (match reference)
constexpr int B = 128, N = 900, C = 91, M = 100;
constexpr float ALPHA = 0.25f;
constexpr float W_CLASS = 2.0f;
constexpr float W_BBOX = 5.0f;
constexpr float W_GIOU = 2.0f;

constexpr int ROWS = 36;          // n-rows per block (900 = 36 * 25)
constexpr int NBX  = N / ROWS;    // 25 blocks in n per batch
constexpr int BLK  = 256;
constexpr int MQ   = M / 4;       // 25 output quads per row
constexpr int NGRP = BLK / MQ;    // 10 complete row-groups (tids 250..255 idle in C)

__global__ __launch_bounds__(BLK) void hungarian_cost_kernel(
    const float* __restrict__ logits,   // [B, N, C]
    const float* __restrict__ pboxes,   // [B, N, 4] cxcywh
    const int*   __restrict__ tlabels,  // [B, M]
    const float* __restrict__ tboxes,   // [B, M, 4] cxcywh
    float* __restrict__ out)            // [B, N, M]
{
    __shared__ float cls[ROWS][C + 1];  // class cost, pre-scaled by W_CLASS
    __shared__ float pb[ROWS][10];      // pred: cx,cy,w,h,x0,y0,x1,y1,area

    const int b   = blockIdx.y;
    const int n0  = blockIdx.x * ROWS;
    const int tid = threadIdx.x;

    const int  mq     = tid % MQ;       // 0..24 (quad of m)
    const int  rgrp   = tid / MQ;       // 0..10
    const bool active = (rgrp < NGRP);

    // ---- Per-thread targets -> registers (global reads, L2-resident) ----
    float tcx[4], tcy[4], twd[4], tht[4];
    float tx0[4], ty0[4], tx1[4], ty1[4], tar[4];
    int   labj[4];
    if (active) {
        const float4* tbp = reinterpret_cast<const float4*>(tboxes) + (size_t)b * M;
        const int4 l4 = reinterpret_cast<const int4*>(tlabels + (size_t)b * M)[mq];
        labj[0] = l4.x; labj[1] = l4.y; labj[2] = l4.z; labj[3] = l4.w;
        #pragma unroll
        for (int j = 0; j < 4; ++j) {
            const float4 t = tbp[mq * 4 + j];
            tcx[j] = t.x; tcy[j] = t.y; twd[j] = t.z; tht[j] = t.w;
            tx0[j] = t.x - 0.5f * t.z;  ty0[j] = t.y - 0.5f * t.w;
            tx1[j] = t.x + 0.5f * t.z;  ty1[j] = t.y + 0.5f * t.w;
            tar[j] = (tx1[j] - tx0[j]) * (ty1[j] - ty0[j]);
        }
    }

    // ---- Stage pred boxes (threads 0..35) ----
    if (tid < ROWS) {
        const float4 p = reinterpret_cast<const float4*>(pboxes)[b * N + n0 + tid];
        const float x0 = p.x - 0.5f * p.z, y0 = p.y - 0.5f * p.w;
        const float x1 = p.x + 0.5f * p.z, y1 = p.y + 0.5f * p.w;
        pb[tid][0] = p.x; pb[tid][1] = p.y; pb[tid][2] = p.z; pb[tid][3] = p.w;
        pb[tid][4] = x0;  pb[tid][5] = y0;  pb[tid][6] = x1;  pb[tid][7] = y1;
        pb[tid][8] = (x1 - x0) * (y1 - y0);
    }

    // ---- Focal class costs: 1 exp + 1 log per element ----
    // s = 1/(1+e), e = exp(-x);  -log(s) = log(1+e);  -log(1-s) = x + log(1+e)
    const float* lrow = logits + ((size_t)b * N + n0) * C;
    for (int idx = tid; idx < ROWS * C; idx += BLK) {
        const float x = lrow[idx];
        const int row = idx / C;
        const int c   = idx - row * C;
        const float e    = __expf(-x);
        const float onep = 1.0f + e;
        const float s    = __fdividef(1.0f, onep);
        const float om   = e * s;               // 1 - s
        const float L    = __logf(onep);        // = -log(s)
        cls[row][c] = W_CLASS * (ALPHA * om * om * L
                               - (1.0f - ALPHA) * s * s * (x + L));
    }
    __syncthreads();

    // ---- Outputs: fixed m-quad per thread, loop rows; targets in regs ----
    if (active) {
        float4* outq = reinterpret_cast<float4*>(out) + (size_t)(b * N + n0) * MQ;
        for (int row = rgrp; row < ROWS; row += NGRP) {
            const float pcx = pb[row][0], pcy = pb[row][1], pw = pb[row][2], ph = pb[row][3];
            const float px0 = pb[row][4], py0 = pb[row][5], px1 = pb[row][6], py1 = pb[row][7];
            const float parea = pb[row][8];

            float4 res;
            float* rp = &res.x;
            #pragma unroll
            for (int j = 0; j < 4; ++j) {
                const float l1 = fabsf(pcx - tcx[j]) + fabsf(pcy - tcy[j]) +
                                 fabsf(pw  - twd[j]) + fabsf(ph  - tht[j]);

                const float iw = fmaxf(fminf(px1, tx1[j]) - fmaxf(px0, tx0[j]), 0.0f);
                const float ih = fmaxf(fminf(py1, ty1[j]) - fmaxf(py0, ty0[j]), 0.0f);
                const float inter = iw * ih;
                const float uni = parea + tar[j] - inter;

                const float ew = fmaxf(px1, tx1[j]) - fminf(px0, tx0[j]);
                const float eh = fmaxf(py1, ty1[j]) - fminf(py0, ty0[j]);
                const float earea = ew * eh;

                const float giou = __fdividef(inter, uni)
                                 - __fdividef(earea - uni, earea);

                rp[j] = cls[row][labj[j]] + W_BBOX * l1 - W_GIOU * giou;
            }
            outq[(size_t)row * MQ + mq] = res;
        }
    }
}

extern "C" void kernel_launch(void* const* d_in, const int* in_sizes, int n_in,
                              void* d_out, int out_size, void* d_ws, size_t ws_size,
                              hipStream_t stream) {
    const float* logits  = (const float*)d_in[0];
    const float* pboxes  = (const float*)d_in[1];
    const int*   tlabels = (const int*)d_in[2];
    const float* tboxes  = (const float*)d_in[3];
    float* out = (float*)d_out;

    dim3 grid(NBX, B);
    dim3 block(BLK);
    hipLaunchKernelGGL(hungarian_cost_kernel, grid, block, 0, stream,
                       logits, pboxes, tlabels, tboxes, out);
}

// Round 4
// 37.650 us; speedup vs baseline: 1.6263x; 1.1438x over previous
//
#include <hip/hip_runtime.h>

// Problem constants (match reference)
constexpr int B = 128, N = 900, C = 91, M = 100;
constexpr float ALPHA = 0.25f;
constexpr float W_CLASS = 2.0f;
constexpr float W_BBOX = 5.0f;
constexpr float W_GIOU = 2.0f;

constexpr int ROWS = 36;          // n-rows per block (900 = 36 * 25)
constexpr int NBX  = N / ROWS;    // 25 blocks in n per batch
constexpr int BLK  = 256;
constexpr int MQ   = M / 4;       // 25 output quads per row
constexpr int NGRP = 10;          // row-groups; 250 active threads
constexpr int KIT  = 4;           // ceil(ROWS / NGRP)

__global__ __launch_bounds__(BLK) void hungarian_cost_kernel(
    const float* __restrict__ logits,   // [B, N, C]
    const float* __restrict__ pboxes,   // [B, N, 4] cxcywh
    const int*   __restrict__ tlabels,  // [B, M]
    const float* __restrict__ tboxes,   // [B, M, 4] cxcywh
    float* __restrict__ out)            // [B, N, M]
{
    const int b   = blockIdx.y;
    const int n0  = blockIdx.x * ROWS;
    const int tid = threadIdx.x;

    const int mq   = tid % MQ;        // 0..24 (quad of m)
    const int rgrp = tid / MQ;        // 0..10
    if (rgrp >= NGRP) return;         // 6 idle threads; no barriers below

    // ---- Per-thread targets -> registers (L2-resident re-reads) ----
    float tcx[4], tcy[4], twd[4], tht[4];
    float tx0[4], ty0[4], tx1[4], ty1[4], tar[4];
    int   labj[4];
    {
        const float4* tbp = reinterpret_cast<const float4*>(tboxes) + (size_t)b * M;
        const int4 l4 = reinterpret_cast<const int4*>(tlabels + (size_t)b * M)[mq];
        labj[0] = l4.x; labj[1] = l4.y; labj[2] = l4.z; labj[3] = l4.w;
        #pragma unroll
        for (int j = 0; j < 4; ++j) {
            const float4 t = tbp[mq * 4 + j];
            tcx[j] = t.x; tcy[j] = t.y; twd[j] = t.z; tht[j] = t.w;
            tx0[j] = t.x - 0.5f * t.z;  ty0[j] = t.y - 0.5f * t.w;
            tx1[j] = t.x + 0.5f * t.z;  ty1[j] = t.y + 0.5f * t.w;
            tar[j] = (tx1[j] - tx0[j]) * (ty1[j] - ty0[j]);
        }
    }

    const float*  lbase = logits + ((size_t)b * N + n0) * C;
    const float4* pbp   = reinterpret_cast<const float4*>(pboxes) + (size_t)b * N + n0;
    float4*       outq  = reinterpret_cast<float4*>(out) + ((size_t)b * N + n0) * MQ;

    // ---- Fully unrolled row loop: 4 iters, clamped row, predicated store ----
    #pragma unroll
    for (int k = 0; k < KIT; ++k) {
        const int rowv = rgrp + NGRP * k;
        const int row  = (rowv < ROWS) ? rowv : (ROWS - 1);   // clamp: safe loads

        // pred box (wave-broadcast address within a row-group)
        const float4 p = pbp[row];
        const float px0 = p.x - 0.5f * p.z, py0 = p.y - 0.5f * p.w;
        const float px1 = p.x + 0.5f * p.z, py1 = p.y + 0.5f * p.w;
        const float parea = (px1 - px0) * (py1 - py0);

        // gathered logits for this thread's 4 labels (L1-resident row)
        const float* lr = lbase + row * C;
        float xs[4];
        #pragma unroll
        for (int j = 0; j < 4; ++j) xs[j] = lr[labj[j]];

        float4 res;
        float* rp = &res.x;
        #pragma unroll
        for (int j = 0; j < 4; ++j) {
            // focal class cost:  s = 1/(1+e), e = exp(-x)
            // -log(s) = log(1+e);  -log(1-s) = x + log(1+e)
            const float x    = xs[j];
            const float e    = __expf(-x);
            const float onep = 1.0f + e;
            const float s    = __fdividef(1.0f, onep);
            const float om   = e * s;            // 1 - s
            const float L    = __logf(onep);     // = -log(s)
            const float ccls = W_CLASS * (ALPHA * om * om * L
                                        - (1.0f - ALPHA) * s * s * (x + L));

            // L1 cdist on cxcywh
            const float l1 = fabsf(p.x - tcx[j]) + fabsf(p.y - tcy[j]) +
                             fabsf(p.z - twd[j]) + fabsf(p.w - tht[j]);

            // GIoU on xyxy
            const float iw = fmaxf(fminf(px1, tx1[j]) - fmaxf(px0, tx0[j]), 0.0f);
            const float ih = fmaxf(fminf(py1, ty1[j]) - fmaxf(py0, ty0[j]), 0.0f);
            const float inter = iw * ih;
            const float uni   = parea + tar[j] - inter;

            const float ew = fmaxf(px1, tx1[j]) - fminf(px0, tx0[j]);
            const float eh = fmaxf(py1, ty1[j]) - fminf(py0, ty0[j]);
            const float earea = ew * eh;

            const float giou = __fdividef(inter, uni)
                             - __fdividef(earea - uni, earea);

            rp[j] = ccls + W_BBOX * l1 - W_GIOU * giou;
        }

        if (rowv < ROWS) outq[(size_t)row * MQ + mq] = res;
    }
}

extern "C" void kernel_launch(void* const* d_in, const int* in_sizes, int n_in,
                              void* d_out, int out_size, void* d_ws, size_t ws_size,
                              hipStream_t stream) {
    const float* logits  = (const float*)d_in[0];
    const float* pboxes  = (const float*)d_in[1];
    const int*   tlabels = (const int*)d_in[2];
    const float* tboxes  = (const float*)d_in[3];
    float* out = (float*)d_out;

    dim3 grid(NBX, B);
    dim3 block(BLK);
    hipLaunchKernelGGL(hungarian_cost_kernel, grid, block, 0, stream,
                       logits, pboxes, tlabels, tboxes, out);
}

// Round 5
// 36.093 us; speedup vs baseline: 1.6965x; 1.0431x over previous
//
#include <hip/hip_runtime.h>

// Problem constants (match reference)
constexpr int B = 128, N = 900, C = 91, M = 100;
constexpr float ALPHA = 0.25f;
constexpr float W_CLASS = 2.0f;
constexpr float W_BBOX = 5.0f;
constexpr float W_GIOU = 2.0f;

constexpr int NBX  = 15;          // blocks in n per batch
constexpr int ROWS = N / NBX;     // 60 rows per block
constexpr int BLK  = 256;
constexpr int MQ   = M / 4;       // 25 output quads per row
constexpr int NGRP = 10;          // row-groups; 250 active threads
constexpr int KIT  = ROWS / NGRP; // 6 iterations per thread (exact)

__global__ __launch_bounds__(BLK) void hungarian_cost_kernel(
    const float* __restrict__ logits,   // [B, N, C]
    const float* __restrict__ pboxes,   // [B, N, 4] cxcywh
    const int*   __restrict__ tlabels,  // [B, M]
    const float* __restrict__ tboxes,   // [B, M, 4] cxcywh
    float* __restrict__ out)            // [B, N, M]
{
    const int b   = blockIdx.y;
    const int n0  = blockIdx.x * ROWS;
    const int tid = threadIdx.x;

    const int mq   = tid % MQ;        // 0..24 (quad of m)
    const int rgrp = tid / MQ;        // 0..10
    if (rgrp >= NGRP) return;         // 6 idle threads; no barriers anywhere

    // ---- Per-thread targets -> registers, loaded ONCE per block ----
    float tcx[4], tcy[4], twd[4], tht[4];
    float tx0[4], ty0[4], tx1[4], ty1[4], tar[4];
    int   labj[4];
    {
        const float4* tbp = reinterpret_cast<const float4*>(tboxes) + (size_t)b * M;
        const int4 l4 = reinterpret_cast<const int4*>(tlabels + (size_t)b * M)[mq];
        labj[0] = l4.x; labj[1] = l4.y; labj[2] = l4.z; labj[3] = l4.w;
        #pragma unroll
        for (int j = 0; j < 4; ++j) {
            const float4 t = tbp[mq * 4 + j];
            tcx[j] = t.x; tcy[j] = t.y; twd[j] = t.z; tht[j] = t.w;
            tx0[j] = t.x - 0.5f * t.z;  ty0[j] = t.y - 0.5f * t.w;
            tx1[j] = t.x + 0.5f * t.z;  ty1[j] = t.y + 0.5f * t.w;
            tar[j] = (tx1[j] - tx0[j]) * (ty1[j] - ty0[j]);
        }
    }

    const float*  lbase = logits + ((size_t)b * N + n0) * C;
    const float4* pbp   = reinterpret_cast<const float4*>(pboxes) + (size_t)b * N + n0;
    float4*       outq  = reinterpret_cast<float4*>(out) + ((size_t)b * N + n0) * MQ;

    // ---- Row loop: 6 iterations, keep VGPR low (TLP hides latency) ----
    #pragma unroll 1
    for (int k = 0; k < KIT; ++k) {
        const int row = rgrp + NGRP * k;

        // pred box (wave-broadcast address within a row-group)
        const float4 p = pbp[row];

        // gathered logits for this thread's 4 labels (L1-resident row)
        const float* lr = lbase + row * C;
        float xs[4];
        #pragma unroll
        for (int j = 0; j < 4; ++j) xs[j] = lr[labj[j]];

        const float px0 = p.x - 0.5f * p.z, py0 = p.y - 0.5f * p.w;
        const float px1 = p.x + 0.5f * p.z, py1 = p.y + 0.5f * p.w;
        const float parea = (px1 - px0) * (py1 - py0);

        float4 res;
        float* rp = &res.x;
        #pragma unroll
        for (int j = 0; j < 4; ++j) {
            // focal class cost:  s = 1/(1+e), e = exp(-x)
            // -log(s) = log(1+e);  -log(1-s) = x + log(1+e)
            const float x    = xs[j];
            const float e    = __expf(-x);
            const float onep = 1.0f + e;
            const float s    = __fdividef(1.0f, onep);
            const float om   = e * s;            // 1 - s
            const float L    = __logf(onep);     // = -log(s)
            const float ccls = W_CLASS * (ALPHA * om * om * L
                                        - (1.0f - ALPHA) * s * s * (x + L));

            // L1 cdist on cxcywh
            const float l1 = fabsf(p.x - tcx[j]) + fabsf(p.y - tcy[j]) +
                             fabsf(p.z - twd[j]) + fabsf(p.w - tht[j]);

            // GIoU on xyxy, single reciprocal:
            // giou = inter/uni - (earea-uni)/earea
            //      = (inter*earea - uni*(earea-uni)) / (uni*earea)
            const float iw = fmaxf(fminf(px1, tx1[j]) - fmaxf(px0, tx0[j]), 0.0f);
            const float ih = fmaxf(fminf(py1, ty1[j]) - fmaxf(py0, ty0[j]), 0.0f);
            const float inter = iw * ih;
            const float uni   = parea + tar[j] - inter;

            const float ew = fmaxf(px1, tx1[j]) - fminf(px0, tx0[j]);
            const float eh = fmaxf(py1, ty1[j]) - fminf(py0, ty0[j]);
            const float earea = ew * eh;

            const float num  = inter * earea - uni * (earea - uni);
            const float rcpD = __frcp_rn(uni * earea);

            rp[j] = ccls + W_BBOX * l1 - W_GIOU * (num * rcpD);
        }

        outq[(size_t)row * MQ + mq] = res;
    }
}

extern "C" void kernel_launch(void* const* d_in, const int* in_sizes, int n_in,
                              void* d_out, int out_size, void* d_ws, size_t ws_size,
                              hipStream_t stream) {
    const float* logits  = (const float*)d_in[0];
    const float* pboxes  = (const float*)d_in[1];
    const int*   tlabels = (const int*)d_in[2];
    const float* tboxes  = (const float*)d_in[3];
    float* out = (float*)d_out;

    dim3 grid(NBX, B);
    dim3 block(BLK);
    hipLaunchKernelGGL(hungarian_cost_kernel, grid, block, 0, stream,
                       logits, pboxes, tlabels, tboxes, out);
}

// Round 6
// 28.919 us; speedup vs baseline: 2.1173x; 1.2481x over previous
//
#include <hip/hip_runtime.h>

// Problem constants (match reference)
constexpr int B = 128, N = 900, C = 91, M = 100;
constexpr float ALPHA = 0.25f;
constexpr float W_CLASS = 2.0f;
constexpr float W_BBOX = 5.0f;
constexpr float W_GIOU = 2.0f;

constexpr int NBX  = 15;          // blocks in n per batch
constexpr int ROWS = N / NBX;     // 60 rows per block
constexpr int BLK  = 256;
constexpr int MQ   = M / 4;       // 25 output quads per row
constexpr int NGRP = 10;          // row-groups; 250 active threads
constexpr int KIT  = ROWS / NGRP; // 6 iterations per thread (exact)

__global__ __launch_bounds__(BLK) void hungarian_cost_kernel(
    const float* __restrict__ logits,   // [B, N, C]
    const float* __restrict__ pboxes,   // [B, N, 4] cxcywh
    const int*   __restrict__ tlabels,  // [B, M]
    const float* __restrict__ tboxes,   // [B, M, 4] cxcywh
    float* __restrict__ out)            // [B, N, M]
{
    const int b   = blockIdx.y;
    const int n0  = blockIdx.x * ROWS;
    const int tid = threadIdx.x;

    const int mq   = tid % MQ;        // 0..24 (quad of m)
    const int rgrp = tid / MQ;        // 0..10
    if (rgrp >= NGRP) return;         // 6 idle threads; no barriers anywhere

    const float*  lbase = logits + ((size_t)b * N + n0) * C;
    const float4* pbp   = reinterpret_cast<const float4*>(pboxes) + (size_t)b * N + n0;
    float4*       outq  = reinterpret_cast<float4*>(out) + ((size_t)b * N + n0) * MQ;

    // ---- Load labels first (gather addresses depend on them) ----
    const int4 l4 = reinterpret_cast<const int4*>(tlabels + (size_t)b * M)[mq];
    int labj[4] = {l4.x, l4.y, l4.z, l4.w};

    // ---- Issue ALL hot-loop loads up front: 6 pred-box + 24 logit gathers ----
    float4 pv[KIT];
    float  xsv[KIT][4];
    #pragma unroll
    for (int k = 0; k < KIT; ++k) {
        const int row = rgrp + NGRP * k;
        pv[k] = pbp[row];
        const float* lr = lbase + row * C;
        #pragma unroll
        for (int j = 0; j < 4; ++j) xsv[k][j] = lr[labj[j]];
    }

    // ---- Targets -> registers (loaded once, reused 6x) ----
    float tcx[4], tcy[4], twd[4], tht[4];
    float tx0[4], ty0[4], tx1[4], ty1[4], tar[4];
    {
        const float4* tbp = reinterpret_cast<const float4*>(tboxes) + (size_t)b * M;
        #pragma unroll
        for (int j = 0; j < 4; ++j) {
            const float4 t = tbp[mq * 4 + j];
            tcx[j] = t.x; tcy[j] = t.y; twd[j] = t.z; tht[j] = t.w;
            tx0[j] = t.x - 0.5f * t.z;  ty0[j] = t.y - 0.5f * t.w;
            tx1[j] = t.x + 0.5f * t.z;  ty1[j] = t.y + 0.5f * t.w;
            tar[j] = (tx1[j] - tx0[j]) * (ty1[j] - ty0[j]);
        }
    }

    // ---- Compute all 6 iterations against in-flight loads ----
    #pragma unroll
    for (int k = 0; k < KIT; ++k) {
        const int row = rgrp + NGRP * k;
        const float4 p = pv[k];

        const float px0 = p.x - 0.5f * p.z, py0 = p.y - 0.5f * p.w;
        const float px1 = p.x + 0.5f * p.z, py1 = p.y + 0.5f * p.w;
        const float parea = (px1 - px0) * (py1 - py0);

        float4 res;
        float* rp = &res.x;
        #pragma unroll
        for (int j = 0; j < 4; ++j) {
            // focal class cost:  s = 1/(1+e), e = exp(-x)
            // -log(s) = log(1+e);  -log(1-s) = x + log(1+e)
            const float x    = xsv[k][j];
            const float e    = __expf(-x);
            const float onep = 1.0f + e;
            const float s    = __builtin_amdgcn_rcpf(onep);
            const float om   = e * s;            // 1 - s
            const float L    = __logf(onep);     // = -log(s)
            const float ccls = W_CLASS * (ALPHA * om * om * L
                                        - (1.0f - ALPHA) * s * s * (x + L));

            // L1 cdist on cxcywh
            const float l1 = fabsf(p.x - tcx[j]) + fabsf(p.y - tcy[j]) +
                             fabsf(p.z - twd[j]) + fabsf(p.w - tht[j]);

            // GIoU on xyxy, single reciprocal:
            // giou = (inter*earea - uni*(earea-uni)) / (uni*earea)
            const float iw = fmaxf(fminf(px1, tx1[j]) - fmaxf(px0, tx0[j]), 0.0f);
            const float ih = fmaxf(fminf(py1, ty1[j]) - fmaxf(py0, ty0[j]), 0.0f);
            const float inter = iw * ih;
            const float uni   = parea + tar[j] - inter;

            const float ew = fmaxf(px1, tx1[j]) - fminf(px0, tx0[j]);
            const float eh = fmaxf(py1, ty1[j]) - fminf(py0, ty0[j]);
            const float earea = ew * eh;

            const float num  = inter * earea - uni * (earea - uni);
            const float rcpD = __builtin_amdgcn_rcpf(uni * earea);

            rp[j] = ccls + W_BBOX * l1 - W_GIOU * (num * rcpD);
        }

        outq[(size_t)row * MQ + mq] = res;
    }
}

extern "C" void kernel_launch(void* const* d_in, const int* in_sizes, int n_in,
                              void* d_out, int out_size, void* d_ws, size_t ws_size,
                              hipStream_t stream) {
    const float* logits  = (const float*)d_in[0];
    const float* pboxes  = (const float*)d_in[1];
    const int*   tlabels = (const int*)d_in[2];
    const float* tboxes  = (const float*)d_in[3];
    float* out = (float*)d_out;

    dim3 grid(NBX, B);
    dim3 block(BLK);
    hipLaunchKernelGGL(hungarian_cost_kernel, grid, block, 0, stream,
                       logits, pboxes, tlabels, tboxes, out);
}